// Round 1
// baseline (1073.517 us; speedup 1.0000x reference)
//
#include <hip/hip_runtime.h>
#include <cstdint>
#include <cstddef>

#define B_SZ 4096
#define H_SZ 2048
#define S_SZ 3

typedef __attribute__((ext_vector_type(8))) short bf16x8;   // 8 bf16 (4 VGPRs)
typedef __attribute__((ext_vector_type(4))) float f32x4;
typedef __attribute__((ext_vector_type(4))) unsigned short us4;

__device__ __forceinline__ unsigned short f2bf(float f) {
    union { float f; unsigned u; } c; c.f = f;
    unsigned r = c.u + 0x7fffu + ((c.u >> 16) & 1u);   // round-to-nearest-even
    return (unsigned short)(r >> 16);
}
__device__ __forceinline__ float bf2f(unsigned short h) {
    union { float f; unsigned u; } c; c.u = ((unsigned)h) << 16;
    return c.f;
}

__device__ __forceinline__ float wave_red_sum(float v) {
#pragma unroll
    for (int off = 32; off > 0; off >>= 1) v += __shfl_down(v, off);
    return v;
}

// ---------------------------------------------------------------- gate ------
// logits = prev_master @ gate_W^T + gate_b ; z = logits + gumbel (TAU=1)
// y = softmax(z); gate = onehot(argmax(y)) + y - y   (forward == hard one-hot)
__global__ __launch_bounds__(64) void gate_kernel(
    const float* __restrict__ prev_master, const float* __restrict__ gate_W,
    const float* __restrict__ gate_b, const float* __restrict__ gumbel,
    float* __restrict__ out_gate)
{
    const int b = blockIdx.x;
    const int lane = threadIdx.x;
    const float* row = prev_master + (size_t)b * H_SZ;
    double a0 = 0.0, a1 = 0.0, a2 = 0.0;
#pragma unroll
    for (int k = lane * 4; k < H_SZ; k += 64 * 4) {
        float4 v  = *(const float4*)(row + k);
        float4 w0 = *(const float4*)(gate_W + 0 * H_SZ + k);
        float4 w1 = *(const float4*)(gate_W + 1 * H_SZ + k);
        float4 w2 = *(const float4*)(gate_W + 2 * H_SZ + k);
        a0 += (double)v.x * w0.x + (double)v.y * w0.y + (double)v.z * w0.z + (double)v.w * w0.w;
        a1 += (double)v.x * w1.x + (double)v.y * w1.y + (double)v.z * w1.z + (double)v.w * w1.w;
        a2 += (double)v.x * w2.x + (double)v.y * w2.y + (double)v.z * w2.z + (double)v.w * w2.w;
    }
#pragma unroll
    for (int off = 32; off > 0; off >>= 1) {
        a0 += __shfl_down(a0, off);
        a1 += __shfl_down(a1, off);
        a2 += __shfl_down(a2, off);
    }
    if (lane == 0) {
        float z0 = (float)a0 + gate_b[0] + gumbel[b * 3 + 0];
        float z1 = (float)a1 + gate_b[1] + gumbel[b * 3 + 1];
        float z2 = (float)a2 + gate_b[2] + gumbel[b * 3 + 2];
        float zm = fmaxf(z0, fmaxf(z1, z2));
        float e0 = expf(z0 - zm), e1 = expf(z1 - zm), e2 = expf(z2 - zm);
        float se = e0 + e1 + e2;
        float y0 = e0 / se, y1 = e1 / se, y2 = e2 / se;
        int am = 0; float best = y0;
        if (y1 > best) { best = y1; am = 1; }
        if (y2 > best) { best = y2; am = 2; }
        float h0 = (am == 0) ? 1.0f : 0.0f;
        float h1 = (am == 1) ? 1.0f : 0.0f;
        float h2 = (am == 2) ? 1.0f : 0.0f;
        out_gate[b * 3 + 0] = (h0 + y0) - y0;
        out_gate[b * 3 + 1] = (h1 + y1) - y1;
        out_gate[b * 3 + 2] = (h2 + y2) - y2;
    }
}

// ----------------------------------------------------------- sub-cell GEMM --
// new_sub[s,b,h] = tanh( x[b,:]·W_ih[s,h,:] + prev_sub[s,b,:]·W_hh[s,h,:] + bias )
// 128x128 tile, BK=32, 4 waves, 16x16x32 bf16 MFMA.
// Precision: A split hi+lo bf16 (2 MFMA passes), W single bf16.
__global__ __launch_bounds__(256) void sub_gemm_kernel(
    const float* __restrict__ x, const float* __restrict__ prev_sub,
    const float* __restrict__ W_ih, const float* __restrict__ W_hh,
    const float* __restrict__ b_ih, const float* __restrict__ b_hh,
    float* __restrict__ out_new_sub)
{
    const int s  = blockIdx.z;
    const int n0 = blockIdx.x * 128;   // h tile
    const int m0 = blockIdx.y * 128;   // b tile

    __shared__ unsigned short lds_a_hi[128 * 32];
    __shared__ unsigned short lds_a_lo[128 * 32];
    __shared__ unsigned short lds_w[128 * 32];

    const int tid  = threadIdx.x;
    const int lane = tid & 63;
    const int wave = tid >> 6;
    const int wm = (wave >> 1) * 64;
    const int wn = (wave & 1) * 64;
    const int lrow = lane & 15;          // C col / frag row
    const int lk   = (lane >> 4) * 8;    // frag k offset

    f32x4 acc[4][4] = {};

    const int sc = (tid & 7) * 4;        // k offset within tile
    const int sr = tid >> 3;             // 0..31

    for (int phase = 0; phase < 2; ++phase) {
        const float* Asrc = phase ? (prev_sub + (size_t)s * B_SZ * H_SZ) : x;
        const float* Wsrc = (phase ? W_hh : W_ih) + (size_t)s * H_SZ * 2048;
        for (int kt = 0; kt < 2048; kt += 32) {
#pragma unroll
            for (int r = 0; r < 4; ++r) {
                const int row = sr + r * 32;
                float4 v = *(const float4*)(Asrc + (size_t)(m0 + row) * 2048 + kt + sc);
                us4 hi, lo;
                unsigned short h;
                h = f2bf(v.x); hi.x = h; lo.x = f2bf(v.x - bf2f(h));
                h = f2bf(v.y); hi.y = h; lo.y = f2bf(v.y - bf2f(h));
                h = f2bf(v.z); hi.z = h; lo.z = f2bf(v.z - bf2f(h));
                h = f2bf(v.w); hi.w = h; lo.w = f2bf(v.w - bf2f(h));
                *(us4*)&lds_a_hi[row * 32 + sc] = hi;
                *(us4*)&lds_a_lo[row * 32 + sc] = lo;
                float4 wv = *(const float4*)(Wsrc + (size_t)(n0 + row) * 2048 + kt + sc);
                us4 wh;
                wh.x = f2bf(wv.x); wh.y = f2bf(wv.y); wh.z = f2bf(wv.z); wh.w = f2bf(wv.w);
                *(us4*)&lds_w[row * 32 + sc] = wh;
            }
            __syncthreads();
            bf16x8 afh[4], afl[4], wf[4];
#pragma unroll
            for (int i = 0; i < 4; ++i) {
                afh[i] = *(const bf16x8*)&lds_a_hi[(wm + i * 16 + lrow) * 32 + lk];
                afl[i] = *(const bf16x8*)&lds_a_lo[(wm + i * 16 + lrow) * 32 + lk];
                wf[i]  = *(const bf16x8*)&lds_w[(wn + i * 16 + lrow) * 32 + lk];
            }
#pragma unroll
            for (int i = 0; i < 4; ++i)
#pragma unroll
                for (int j = 0; j < 4; ++j) {
                    acc[i][j] = __builtin_amdgcn_mfma_f32_16x16x32_bf16(afh[i], wf[j], acc[i][j], 0, 0, 0);
                    acc[i][j] = __builtin_amdgcn_mfma_f32_16x16x32_bf16(afl[i], wf[j], acc[i][j], 0, 0, 0);
                }
            __syncthreads();
        }
    }
    // epilogue: C[m,n] layout: n = lane&15, m = (lane>>4)*4 + reg
#pragma unroll
    for (int j = 0; j < 4; ++j) {
        const int n = n0 + wn + j * 16 + lrow;
        const float bias = b_ih[s * H_SZ + n] + b_hh[s * H_SZ + n];
#pragma unroll
        for (int i = 0; i < 4; ++i) {
            const int mbase = m0 + wm + i * 16 + (lane >> 4) * 4;
#pragma unroll
            for (int r = 0; r < 4; ++r) {
                const int m = mbase + r;
                out_new_sub[((size_t)s * B_SZ + m) * H_SZ + n] = tanhf(acc[i][j][r] + bias);
            }
        }
    }
}

// ------------------------------------------------------------- weighted -----
// weighted[b,h] = sum_s gate[b,s]*new_sub[s,b,h]; store as bf16 hi/lo planes.
__global__ __launch_bounds__(256) void weighted_kernel(
    const float* __restrict__ new_sub, const float* __restrict__ gate,
    unsigned short* __restrict__ w_hi, unsigned short* __restrict__ w_lo)
{
    const size_t p = (size_t)blockIdx.x * 256 + threadIdx.x;   // float4 index
    const size_t b = p / (H_SZ / 4);
    const int h4 = (int)(p % (H_SZ / 4)) * 4;
    const float g0 = gate[b * 3 + 0], g1 = gate[b * 3 + 1], g2 = gate[b * 3 + 2];
    const float4 v0 = *(const float4*)(new_sub + ((size_t)0 * B_SZ + b) * H_SZ + h4);
    const float4 v1 = *(const float4*)(new_sub + ((size_t)1 * B_SZ + b) * H_SZ + h4);
    const float4 v2 = *(const float4*)(new_sub + ((size_t)2 * B_SZ + b) * H_SZ + h4);
    float w[4];
    w[0] = g0 * v0.x + g1 * v1.x + g2 * v2.x;
    w[1] = g0 * v0.y + g1 * v1.y + g2 * v2.y;
    w[2] = g0 * v0.z + g1 * v1.z + g2 * v2.z;
    w[3] = g0 * v0.w + g1 * v1.w + g2 * v2.w;
    us4 hi, lo;
#pragma unroll
    for (int e = 0; e < 4; ++e) {
        unsigned short h = f2bf(w[e]);
        hi[e] = h;
        lo[e] = f2bf(w[e] - bf2f(h));
    }
    *(us4*)(w_hi + b * H_SZ + h4) = hi;
    *(us4*)(w_lo + b * H_SZ + h4) = lo;
}

// ------------------------------------------------------------ fusion GEMM ---
// pre[b,h] = weighted[b,:]·fusion_W[h,:] + fusion_b[h] + prev_master[b,h]
__global__ __launch_bounds__(256) void fusion_gemm_kernel(
    const unsigned short* __restrict__ a_hi, const unsigned short* __restrict__ a_lo,
    const float* __restrict__ fusion_W, const float* __restrict__ fusion_b,
    const float* __restrict__ prev_master, float* __restrict__ out_pre)
{
    const int n0 = blockIdx.x * 128;
    const int m0 = blockIdx.y * 128;

    __shared__ unsigned short lds_a_hi[128 * 32];
    __shared__ unsigned short lds_a_lo[128 * 32];
    __shared__ unsigned short lds_w[128 * 32];

    const int tid  = threadIdx.x;
    const int lane = tid & 63;
    const int wave = tid >> 6;
    const int wm = (wave >> 1) * 64;
    const int wn = (wave & 1) * 64;
    const int lrow = lane & 15;
    const int lk   = (lane >> 4) * 8;

    f32x4 acc[4][4] = {};

    const int sc = (tid & 7) * 4;
    const int sr = tid >> 3;

    for (int kt = 0; kt < H_SZ; kt += 32) {
#pragma unroll
        for (int r = 0; r < 4; ++r) {
            const int row = sr + r * 32;
            *(us4*)&lds_a_hi[row * 32 + sc] = *(const us4*)(a_hi + (size_t)(m0 + row) * H_SZ + kt + sc);
            *(us4*)&lds_a_lo[row * 32 + sc] = *(const us4*)(a_lo + (size_t)(m0 + row) * H_SZ + kt + sc);
            float4 wv = *(const float4*)(fusion_W + (size_t)(n0 + row) * H_SZ + kt + sc);
            us4 wh;
            wh.x = f2bf(wv.x); wh.y = f2bf(wv.y); wh.z = f2bf(wv.z); wh.w = f2bf(wv.w);
            *(us4*)&lds_w[row * 32 + sc] = wh;
        }
        __syncthreads();
        bf16x8 afh[4], afl[4], wf[4];
#pragma unroll
        for (int i = 0; i < 4; ++i) {
            afh[i] = *(const bf16x8*)&lds_a_hi[(wm + i * 16 + lrow) * 32 + lk];
            afl[i] = *(const bf16x8*)&lds_a_lo[(wm + i * 16 + lrow) * 32 + lk];
            wf[i]  = *(const bf16x8*)&lds_w[(wn + i * 16 + lrow) * 32 + lk];
        }
#pragma unroll
        for (int i = 0; i < 4; ++i)
#pragma unroll
            for (int j = 0; j < 4; ++j) {
                acc[i][j] = __builtin_amdgcn_mfma_f32_16x16x32_bf16(afh[i], wf[j], acc[i][j], 0, 0, 0);
                acc[i][j] = __builtin_amdgcn_mfma_f32_16x16x32_bf16(afl[i], wf[j], acc[i][j], 0, 0, 0);
            }
        __syncthreads();
    }
#pragma unroll
    for (int j = 0; j < 4; ++j) {
        const int n = n0 + wn + j * 16 + lrow;
        const float fb = fusion_b[n];
#pragma unroll
        for (int i = 0; i < 4; ++i) {
            const int mbase = m0 + wm + i * 16 + (lane >> 4) * 4;
#pragma unroll
            for (int r = 0; r < 4; ++r) {
                const int m = mbase + r;
                out_pre[(size_t)m * H_SZ + n] = acc[i][j][r] + fb + prev_master[(size_t)m * H_SZ + n];
            }
        }
    }
}

// ------------------------------------------------------- layernorm+sigmoid --
// In-place on the master region (block owns the whole row).
__global__ __launch_bounds__(256) void ln_sigmoid_kernel(
    float* __restrict__ master, const float* __restrict__ ln_g,
    const float* __restrict__ ln_b)
{
    const int b = blockIdx.x;
    const int t = threadIdx.x;
    float* row = master + (size_t)b * H_SZ;
    float v[8];
    float4 p0 = *(const float4*)(row + t * 4);
    float4 p1 = *(const float4*)(row + 1024 + t * 4);
    v[0] = p0.x; v[1] = p0.y; v[2] = p0.z; v[3] = p0.w;
    v[4] = p1.x; v[5] = p1.y; v[6] = p1.z; v[7] = p1.w;
    float lsum = 0.f;
#pragma unroll
    for (int e = 0; e < 8; ++e) lsum += v[e];
    __shared__ float red[8];
    float wsum = wave_red_sum(lsum);
    const int lane = t & 63, wid = t >> 6;
    if (lane == 0) red[wid] = wsum;
    __syncthreads();
    const float mu = (red[0] + red[1] + red[2] + red[3]) * (1.0f / H_SZ);
    float lsq = 0.f;
#pragma unroll
    for (int e = 0; e < 8; ++e) { float d = v[e] - mu; lsq += d * d; }
    float wsq = wave_red_sum(lsq);
    if (lane == 0) red[4 + wid] = wsq;
    __syncthreads();
    const float var = (red[4] + red[5] + red[6] + red[7]) * (1.0f / H_SZ);
    const float rs = rsqrtf(var + 1e-5f);
#pragma unroll
    for (int half = 0; half < 2; ++half)
#pragma unroll
        for (int e = 0; e < 4; ++e) {
            const int col = half * 1024 + t * 4 + e;
            const float nm = (v[half * 4 + e] - mu) * rs * ln_g[col] + ln_b[col];
            row[col] = 1.0f / (1.0f + expf(-nm));
        }
}

// ----------------------------------------------------------------- launch ---
extern "C" void kernel_launch(void* const* d_in, const int* in_sizes, int n_in,
                              void* d_out, int out_size, void* d_ws, size_t ws_size,
                              hipStream_t stream)
{
    const float* x           = (const float*)d_in[0];
    const float* prev_master = (const float*)d_in[1];
    const float* prev_sub    = (const float*)d_in[2];
    const float* gumbel      = (const float*)d_in[3];
    const float* W_ih        = (const float*)d_in[4];
    const float* W_hh        = (const float*)d_in[5];
    const float* b_ih        = (const float*)d_in[6];
    const float* b_hh        = (const float*)d_in[7];
    const float* gate_W      = (const float*)d_in[8];
    const float* gate_b      = (const float*)d_in[9];
    const float* fusion_W    = (const float*)d_in[10];
    const float* fusion_b    = (const float*)d_in[11];
    const float* ln_g        = (const float*)d_in[12];
    const float* ln_b        = (const float*)d_in[13];

    float* out = (float*)d_out;
    float* out_master  = out;                                   // [B,H]
    float* out_gate    = out + (size_t)B_SZ * H_SZ;             // [B,S]
    float* out_new_sub = out_gate + (size_t)B_SZ * S_SZ;        // [S,B,H]

    unsigned short* ws_hi = (unsigned short*)d_ws;              // B*H bf16 (16 MB)
    unsigned short* ws_lo = ws_hi + (size_t)B_SZ * H_SZ;        // B*H bf16 (16 MB)

    gate_kernel<<<B_SZ, 64, 0, stream>>>(prev_master, gate_W, gate_b, gumbel, out_gate);
    sub_gemm_kernel<<<dim3(H_SZ / 128, B_SZ / 128, S_SZ), 256, 0, stream>>>(
        x, prev_sub, W_ih, W_hh, b_ih, b_hh, out_new_sub);
    weighted_kernel<<<(B_SZ * (H_SZ / 4)) / 256, 256, 0, stream>>>(
        out_new_sub, out_gate, ws_hi, ws_lo);
    fusion_gemm_kernel<<<dim3(H_SZ / 128, B_SZ / 128), 256, 0, stream>>>(
        ws_hi, ws_lo, fusion_W, fusion_b, prev_master, out_master);
    ln_sigmoid_kernel<<<B_SZ, 256, 0, stream>>>(out_master, ln_g, ln_b);
}

// Round 2
// 756.056 us; speedup vs baseline: 1.4199x; 1.4199x over previous
//
#include <hip/hip_runtime.h>
#include <cstdint>
#include <cstddef>

#define B_SZ 4096
#define H_SZ 2048
#define S_SZ 3

typedef __attribute__((ext_vector_type(8))) _Float16 f16x8;
typedef __attribute__((ext_vector_type(4))) float f32x4;

__device__ __forceinline__ void glds16(const void* g, void* l) {
    __builtin_amdgcn_global_load_lds(
        (const __attribute__((address_space(1))) void*)g,
        (__attribute__((address_space(3))) void*)l, 16, 0, 0);
}

__device__ __forceinline__ float wave_red_sum(float v) {
#pragma unroll
    for (int off = 32; off > 0; off >>= 1) v += __shfl_down(v, off);
    return v;
}

// ------------------------------------------------------------ f32 -> f16 ----
__global__ __launch_bounds__(256) void cvt_f16_kernel(
    const float* __restrict__ src, _Float16* __restrict__ dst, int n4)
{
    const int i = blockIdx.x * 256 + threadIdx.x;
    if (i >= n4) return;
    const float4 v = ((const float4*)src)[i];
    _Float16 h[4];
    h[0] = (_Float16)v.x; h[1] = (_Float16)v.y;
    h[2] = (_Float16)v.z; h[3] = (_Float16)v.w;
    *(uint2*)(dst + (size_t)i * 4) = *(const uint2*)h;
}

// ---------------------------------------------------------------- gate ------
__global__ __launch_bounds__(64) void gate_kernel(
    const float* __restrict__ prev_master, const float* __restrict__ gate_W,
    const float* __restrict__ gate_b, const float* __restrict__ gumbel,
    float* __restrict__ out_gate)
{
    const int b = blockIdx.x;
    const int lane = threadIdx.x;
    const float* row = prev_master + (size_t)b * H_SZ;
    double a0 = 0.0, a1 = 0.0, a2 = 0.0;
#pragma unroll
    for (int k = lane * 4; k < H_SZ; k += 64 * 4) {
        float4 v  = *(const float4*)(row + k);
        float4 w0 = *(const float4*)(gate_W + 0 * H_SZ + k);
        float4 w1 = *(const float4*)(gate_W + 1 * H_SZ + k);
        float4 w2 = *(const float4*)(gate_W + 2 * H_SZ + k);
        a0 += (double)v.x * w0.x + (double)v.y * w0.y + (double)v.z * w0.z + (double)v.w * w0.w;
        a1 += (double)v.x * w1.x + (double)v.y * w1.y + (double)v.z * w1.z + (double)v.w * w1.w;
        a2 += (double)v.x * w2.x + (double)v.y * w2.y + (double)v.z * w2.z + (double)v.w * w2.w;
    }
#pragma unroll
    for (int off = 32; off > 0; off >>= 1) {
        a0 += __shfl_down(a0, off);
        a1 += __shfl_down(a1, off);
        a2 += __shfl_down(a2, off);
    }
    if (lane == 0) {
        float z0 = (float)a0 + gate_b[0] + gumbel[b * 3 + 0];
        float z1 = (float)a1 + gate_b[1] + gumbel[b * 3 + 1];
        float z2 = (float)a2 + gate_b[2] + gumbel[b * 3 + 2];
        float zm = fmaxf(z0, fmaxf(z1, z2));
        float e0 = expf(z0 - zm), e1 = expf(z1 - zm), e2 = expf(z2 - zm);
        float se = e0 + e1 + e2;
        float y0 = e0 / se, y1 = e1 / se, y2 = e2 / se;
        int am = 0; float best = y0;
        if (y1 > best) { best = y1; am = 1; }
        if (y2 > best) { best = y2; am = 2; }
        float h0 = (am == 0) ? 1.0f : 0.0f;
        float h1 = (am == 1) ? 1.0f : 0.0f;
        float h2 = (am == 2) ? 1.0f : 0.0f;
        out_gate[b * 3 + 0] = (h0 + y0) - y0;
        out_gate[b * 3 + 1] = (h1 + y1) - y1;
        out_gate[b * 3 + 2] = (h2 + y2) - y2;
    }
}

// ----------------------------------------------------------- sub-cell GEMM --
// new_sub[s,b,h] = tanh(x·W_ih[s,h,:] + prev_sub[s,b,:]·W_hh[s,h,:] + bias)
// m97 structure: 128x128 tile, BK=32, global_load_lds(16B), fp16 MFMA,
// XOR-swizzled LDS (chunk' = chunk ^ ((row>>1)&3)) -> 2-way (free) frag reads.
__global__ __launch_bounds__(256) void sub_gemm_kernel(
    const _Float16* __restrict__ x16, const _Float16* __restrict__ sub16,
    const _Float16* __restrict__ Wih16, const _Float16* __restrict__ Whh16,
    const float* __restrict__ b_ih, const float* __restrict__ b_hh,
    float* __restrict__ out_new_sub)
{
    const int s  = blockIdx.z;
    const int n0 = blockIdx.x * 128;
    const int m0 = blockIdx.y * 128;

    __shared__ __align__(16) _Float16 lds_a[128 * 32];
    __shared__ __align__(16) _Float16 lds_w[128 * 32];

    const int tid  = threadIdx.x;
    const int lane = tid & 63;
    const int wave = tid >> 6;
    const int wm = (wave >> 1) * 64;
    const int wn = (wave & 1) * 64;
    const int lrow = lane & 15;
    const int lc   = lane >> 4;                      // frag chunk 0..3
    const int fcol = (lc ^ ((lrow >> 1) & 3)) * 8;   // swizzled frag col (elems)

    // staging lane constants (glds: dest = base + lane*16B)
    const int srow   = lane >> 2;                    // row within 16-row group
    const int schunk = (lane & 3) ^ ((lane >> 3) & 3);

    f32x4 acc[4][4] = {};

    for (int phase = 0; phase < 2; ++phase) {
        const _Float16* Asrc = phase ? (sub16 + (size_t)s * B_SZ * 2048) : x16;
        const _Float16* Wsrc = (phase ? Whh16 : Wih16) + (size_t)s * H_SZ * 2048;
        for (int kt = 0; kt < 2048; kt += 32) {
#pragma unroll
            for (int t = 0; t < 2; ++t) {
                const int rb = wave * 32 + t * 16;
                glds16(Asrc + (size_t)(m0 + rb + srow) * 2048 + kt + schunk * 8,
                       &lds_a[rb * 32]);
                glds16(Wsrc + (size_t)(n0 + rb + srow) * 2048 + kt + schunk * 8,
                       &lds_w[rb * 32]);
            }
            __syncthreads();
            f16x8 af[4], wf[4];
#pragma unroll
            for (int i = 0; i < 4; ++i) {
                af[i] = *(const f16x8*)&lds_a[(wm + i * 16 + lrow) * 32 + fcol];
                wf[i] = *(const f16x8*)&lds_w[(wn + i * 16 + lrow) * 32 + fcol];
            }
#pragma unroll
            for (int i = 0; i < 4; ++i)
#pragma unroll
                for (int j = 0; j < 4; ++j)
                    acc[i][j] = __builtin_amdgcn_mfma_f32_16x16x32_f16(af[i], wf[j], acc[i][j], 0, 0, 0);
            __syncthreads();
        }
    }
    // epilogue: C layout col = lane&15, row = (lane>>4)*4 + reg
#pragma unroll
    for (int j = 0; j < 4; ++j) {
        const int n = n0 + wn + j * 16 + lrow;
        const float bias = b_ih[s * H_SZ + n] + b_hh[s * H_SZ + n];
#pragma unroll
        for (int i = 0; i < 4; ++i) {
            const int mbase = m0 + wm + i * 16 + (lane >> 4) * 4;
#pragma unroll
            for (int r = 0; r < 4; ++r) {
                const int m = mbase + r;
                out_new_sub[((size_t)s * B_SZ + m) * H_SZ + n] = tanhf(acc[i][j][r] + bias);
            }
        }
    }
}

// ------------------------------------------------------------- weighted -----
// weighted[b,h] = sum_s gate[b,s]*new_sub[s,b,h] -> fp16 plane in ws.
__global__ __launch_bounds__(256) void weighted_kernel(
    const float* __restrict__ new_sub, const float* __restrict__ gate,
    _Float16* __restrict__ w16)
{
    const size_t p = (size_t)blockIdx.x * 256 + threadIdx.x;   // float4 index
    const size_t b = p / (H_SZ / 4);
    const int h4 = (int)(p % (H_SZ / 4)) * 4;
    const float g0 = gate[b * 3 + 0], g1 = gate[b * 3 + 1], g2 = gate[b * 3 + 2];
    const float4 v0 = *(const float4*)(new_sub + ((size_t)0 * B_SZ + b) * H_SZ + h4);
    const float4 v1 = *(const float4*)(new_sub + ((size_t)1 * B_SZ + b) * H_SZ + h4);
    const float4 v2 = *(const float4*)(new_sub + ((size_t)2 * B_SZ + b) * H_SZ + h4);
    _Float16 h[4];
    h[0] = (_Float16)(g0 * v0.x + g1 * v1.x + g2 * v2.x);
    h[1] = (_Float16)(g0 * v0.y + g1 * v1.y + g2 * v2.y);
    h[2] = (_Float16)(g0 * v0.z + g1 * v1.z + g2 * v2.z);
    h[3] = (_Float16)(g0 * v0.w + g1 * v1.w + g2 * v2.w);
    *(uint2*)(w16 + b * H_SZ + h4) = *(const uint2*)h;
}

// ------------------------------------------------------------ fusion GEMM ---
// pre[b,h] = weighted·fusion_W[h,:] + fusion_b[h] + prev_master[b,h]
__global__ __launch_bounds__(256) void fusion_gemm_kernel(
    const _Float16* __restrict__ a16, const _Float16* __restrict__ w16,
    const float* __restrict__ fusion_b, const float* __restrict__ prev_master,
    float* __restrict__ out_pre)
{
    const int n0 = blockIdx.x * 128;
    const int m0 = blockIdx.y * 128;

    __shared__ __align__(16) _Float16 lds_a[128 * 32];
    __shared__ __align__(16) _Float16 lds_w[128 * 32];

    const int tid  = threadIdx.x;
    const int lane = tid & 63;
    const int wave = tid >> 6;
    const int wm = (wave >> 1) * 64;
    const int wn = (wave & 1) * 64;
    const int lrow = lane & 15;
    const int lc   = lane >> 4;
    const int fcol = (lc ^ ((lrow >> 1) & 3)) * 8;
    const int srow   = lane >> 2;
    const int schunk = (lane & 3) ^ ((lane >> 3) & 3);

    f32x4 acc[4][4] = {};

    for (int kt = 0; kt < H_SZ; kt += 32) {
#pragma unroll
        for (int t = 0; t < 2; ++t) {
            const int rb = wave * 32 + t * 16;
            glds16(a16 + (size_t)(m0 + rb + srow) * H_SZ + kt + schunk * 8,
                   &lds_a[rb * 32]);
            glds16(w16 + (size_t)(n0 + rb + srow) * H_SZ + kt + schunk * 8,
                   &lds_w[rb * 32]);
        }
        __syncthreads();
        f16x8 af[4], wf[4];
#pragma unroll
        for (int i = 0; i < 4; ++i) {
            af[i] = *(const f16x8*)&lds_a[(wm + i * 16 + lrow) * 32 + fcol];
            wf[i] = *(const f16x8*)&lds_w[(wn + i * 16 + lrow) * 32 + fcol];
        }
#pragma unroll
        for (int i = 0; i < 4; ++i)
#pragma unroll
            for (int j = 0; j < 4; ++j)
                acc[i][j] = __builtin_amdgcn_mfma_f32_16x16x32_f16(af[i], wf[j], acc[i][j], 0, 0, 0);
        __syncthreads();
    }
#pragma unroll
    for (int j = 0; j < 4; ++j) {
        const int n = n0 + wn + j * 16 + lrow;
        const float fb = fusion_b[n];
#pragma unroll
        for (int i = 0; i < 4; ++i) {
            const int mbase = m0 + wm + i * 16 + (lane >> 4) * 4;
#pragma unroll
            for (int r = 0; r < 4; ++r) {
                const int m = mbase + r;
                out_pre[(size_t)m * H_SZ + n] = acc[i][j][r] + fb + prev_master[(size_t)m * H_SZ + n];
            }
        }
    }
}

// ------------------------------------------------------- layernorm+sigmoid --
__global__ __launch_bounds__(256) void ln_sigmoid_kernel(
    float* __restrict__ master, const float* __restrict__ ln_g,
    const float* __restrict__ ln_b)
{
    const int b = blockIdx.x;
    const int t = threadIdx.x;
    float* row = master + (size_t)b * H_SZ;
    float v[8];
    float4 p0 = *(const float4*)(row + t * 4);
    float4 p1 = *(const float4*)(row + 1024 + t * 4);
    v[0] = p0.x; v[1] = p0.y; v[2] = p0.z; v[3] = p0.w;
    v[4] = p1.x; v[5] = p1.y; v[6] = p1.z; v[7] = p1.w;
    float lsum = 0.f;
#pragma unroll
    for (int e = 0; e < 8; ++e) lsum += v[e];
    __shared__ float red[8];
    float wsum = wave_red_sum(lsum);
    const int lane = t & 63, wid = t >> 6;
    if (lane == 0) red[wid] = wsum;
    __syncthreads();
    const float mu = (red[0] + red[1] + red[2] + red[3]) * (1.0f / H_SZ);
    float lsq = 0.f;
#pragma unroll
    for (int e = 0; e < 8; ++e) { float d = v[e] - mu; lsq += d * d; }
    float wsq = wave_red_sum(lsq);
    if (lane == 0) red[4 + wid] = wsq;
    __syncthreads();
    const float var = (red[4] + red[5] + red[6] + red[7]) * (1.0f / H_SZ);
    const float rs = rsqrtf(var + 1e-5f);
#pragma unroll
    for (int half = 0; half < 2; ++half)
#pragma unroll
        for (int e = 0; e < 4; ++e) {
            const int col = half * 1024 + t * 4 + e;
            const float nm = (v[half * 4 + e] - mu) * rs * ln_g[col] + ln_b[col];
            row[col] = 1.0f / (1.0f + expf(-nm));
        }
}

// ----------------------------------------------------------------- launch ---
extern "C" void kernel_launch(void* const* d_in, const int* in_sizes, int n_in,
                              void* d_out, int out_size, void* d_ws, size_t ws_size,
                              hipStream_t stream)
{
    const float* x           = (const float*)d_in[0];
    const float* prev_master = (const float*)d_in[1];
    const float* prev_sub    = (const float*)d_in[2];
    const float* gumbel      = (const float*)d_in[3];
    const float* W_ih        = (const float*)d_in[4];
    const float* W_hh        = (const float*)d_in[5];
    const float* b_ih        = (const float*)d_in[6];
    const float* b_hh        = (const float*)d_in[7];
    const float* gate_W      = (const float*)d_in[8];
    const float* gate_b      = (const float*)d_in[9];
    const float* fusion_W    = (const float*)d_in[10];
    const float* fusion_b    = (const float*)d_in[11];
    const float* ln_g        = (const float*)d_in[12];
    const float* ln_b        = (const float*)d_in[13];

    float* out = (float*)d_out;
    float* out_master  = out;                                   // [B,H]
    float* out_gate    = out + (size_t)B_SZ * H_SZ;             // [B,S]
    float* out_new_sub = out_gate + (size_t)B_SZ * S_SZ;        // [S,B,H]

    // ws layout (fp16 planes), ~143 MB total
    _Float16* ws = (_Float16*)d_ws;
    _Float16* x16    = ws;                                      // 8.4M
    _Float16* sub16  = x16   + (size_t)B_SZ * H_SZ;             // 25.2M
    _Float16* Wih16  = sub16 + (size_t)S_SZ * B_SZ * H_SZ;      // 12.6M
    _Float16* Whh16  = Wih16 + (size_t)S_SZ * H_SZ * H_SZ;      // 12.6M
    _Float16* fusW16 = Whh16 + (size_t)S_SZ * H_SZ * H_SZ;      // 4.2M
    _Float16* wtd16  = fusW16 + (size_t)H_SZ * H_SZ;            // 8.4M

    const int n4_x   = B_SZ * H_SZ / 4;
    const int n4_sub = S_SZ * B_SZ * H_SZ / 4;
    const int n4_w   = S_SZ * H_SZ * H_SZ / 4;
    const int n4_fw  = H_SZ * H_SZ / 4;

    cvt_f16_kernel<<<n4_x / 256, 256, 0, stream>>>(x, x16, n4_x);
    cvt_f16_kernel<<<n4_sub / 256, 256, 0, stream>>>(prev_sub, sub16, n4_sub);
    cvt_f16_kernel<<<n4_w / 256, 256, 0, stream>>>(W_ih, Wih16, n4_w);
    cvt_f16_kernel<<<n4_w / 256, 256, 0, stream>>>(W_hh, Whh16, n4_w);
    cvt_f16_kernel<<<n4_fw / 256, 256, 0, stream>>>(fusion_W, fusW16, n4_fw);

    gate_kernel<<<B_SZ, 64, 0, stream>>>(prev_master, gate_W, gate_b, gumbel, out_gate);

    sub_gemm_kernel<<<dim3(H_SZ / 128, B_SZ / 128, S_SZ), 256, 0, stream>>>(
        x16, sub16, Wih16, Whh16, b_ih, b_hh, out_new_sub);

    weighted_kernel<<<(B_SZ * (H_SZ / 4)) / 256, 256, 0, stream>>>(
        out_new_sub, out_gate, wtd16);

    fusion_gemm_kernel<<<dim3(H_SZ / 128, B_SZ / 128), 256, 0, stream>>>(
        wtd16, fusW16, fusion_b, prev_master, out_master);

    ln_sigmoid_kernel<<<B_SZ, 256, 0, stream>>>(out_master, ln_g, ln_b);
}